// Round 13
// baseline (151.622 us; speedup 1.0000x reference)
//
#include <hip/hip_runtime.h>
#include <hip/hip_bf16.h>

#define B_  16
#define E_  8192
#define NN_ 384
#define N1_ 385
#define H_  32
#define HH_ 16                      // h-planes per block (half of H)
#define PLANE_ (N1_ * N1_)          // 148225
#define CAP_ 128                    // per-row list capacity (avg fill ~38)
#define STRIDE_ 396                 // LDS row stride: %4==0 (float4-able)
#define TS_ 17                      // table stride: gcd(17,32)=1 -> bank spread
#define SPAN_ 11                    // rows per block; 385 = 35*11 exactly
#define NSP_ 35
#define GRID_ (B_ * 2 * NSP_)       // 1120 blocks

// ============================================================================
// Single fused kernel: per block = (batch b, h-half, 11-row span).
// Phase 0: stage W1/b1, zero counts.      Phase 1: sort MLP breakpoints.
// Phase 2: build A/B/type tables + scan batch edges -> per-row LDS lists.
// Phase 3: convert entries (edge_feat -> meta,dist).
// Phase 4: barrier-free wave-private row loop (init/gather/store), as verified
//          in rounds 6-12. LDS rows SHIFTED so LDS float4 and global dwordx4
//          are both 16B-aligned. No workspace, no inter-kernel dependencies.
// ============================================================================
__global__ __launch_bounds__(512, 6) void fused_kernel(
    const float4* __restrict__ edge_feat,     // (B,E,4)
    const int*    __restrict__ edge_index,    // (B,2,E)
    const void*   __restrict__ edge_mask,     // (B,E) bool(1B) or int32 — detected
    const int*    __restrict__ nlig,          // (B,)
    const float*  __restrict__ structural_w,  // (20,H)
    const float*  __restrict__ plip_protein_w,// (15,H)
    const float*  __restrict__ plip_ligand_w, // (15,H)
    const float*  __restrict__ plip_inter_w,  // (15,H)
    const float*  __restrict__ loc_w,         // (4,H)
    const float*  __restrict__ virtual_w,     // (1,H)
    const float*  __restrict__ W1,            // (H,1)
    const float*  __restrict__ b1,            // (H,)
    const float*  __restrict__ W2,            // (H,H)
    const float*  __restrict__ b2,            // (H,)
    float* __restrict__ out)                  // (B,H,N1,N1)
{
    __shared__ float4 srow4[HH_ * (STRIDE_ / 4)];   // 25344 B
    __shared__ float sA[33 * TS_], sB[33 * TS_];    // 2244 B each
    __shared__ float sType[66 * TS_];               // 4488 B
    __shared__ float sT[32], sTv[32], sW1[32], sb1[32];
    __shared__ int   sCnt[SPAN_];
    __shared__ int   sListM[SPAN_ * CAP_];          // 5632 B
    __shared__ float sListD[SPAN_ * CAP_];          // 5632 B
    float* srow = reinterpret_cast<float*>(srow4);  // total ~44.9 KB -> 3 blk/CU

    int bid  = blockIdx.x;
    int span = bid % NSP_;
    int rest = bid / NSP_;           // 0..31
    int half = rest & 1;
    int b    = rest >> 1;
    int h0   = half << 4;
    int i0   = span * SPAN_;
    int tid  = threadIdx.x;
    int wv   = tid >> 6, lane = tid & 63;

    // ---- phase 0: stage W1/b1, raw breakpoints, zero counts ----
    if (tid < 32) {
        float w = W1[tid], bb = b1[tid];
        sW1[tid] = w; sb1[tid] = bb;
        sTv[tid] = (w != 0.0f) ? (-bb / w) : -3.402823e38f;
    }
    if (tid < SPAN_) sCnt[tid] = 0;
    __syncthreads();

    // ---- phase 1: stable rank sort of breakpoints ----
    if (tid < 32) {
        float t = sTv[tid];
        int rank = 0;
        for (int j = 0; j < 32; ++j) {
            float tj = sTv[j];
            rank += (tj < t || (tj == t && j < tid)) ? 1 : 0;
        }
        sT[rank] = t;
    }
    __syncthreads();

    // ---- phase 2a: per-segment linear tables for this half ----
    for (int idx = tid; idx < 33 * 16; idx += 512) {
        int s = idx >> 4, hh = idx & 15, h = h0 + hh;
        float m;
        if (s == 0)       m = sT[0] - 1.0f;
        else if (s == 32) m = sT[31] + 1.0f;
        else              m = 0.5f * (sT[s - 1] + sT[s]);
        float alpha = b2[h], beta = 0.0f;
        for (int k = 0; k < 32; ++k) {
            float w = sW1[k], bb = sb1[k];
            bool act = (w > 0.0f) ? (m > -bb / w)
                     : (w < 0.0f) ? (m < -bb / w) : (bb > 0.0f);
            if (act) {
                float w2 = W2[h * 32 + k];
                alpha = fmaf(w2, bb, alpha);
                beta  = fmaf(w2, w, beta);
            }
        }
        sA[s * TS_ + hh] = alpha; sB[s * TS_ + hh] = beta;
    }
    // ---- phase 2b: type-row table for this half ----
    for (int idx = tid; idx < 66 * 16; idx += 512) {
        int r = idx >> 4, hh = idx & 15;
        float v;
        if (r < 20) v = structural_w[r * 32 + h0 + hh];
        else if (r < 65) {
            int t2 = r - 20;
            int loc = t2 / 15, pi = t2 - loc * 15;
            const float* pw = (loc == 0) ? plip_ligand_w
                            : (loc == 1) ? plip_protein_w : plip_inter_w;
            v = pw[pi * 32 + h0 + hh] + loc_w[loc * 32 + h0 + hh];
        } else v = 0.0f;
        sType[r * TS_ + hh] = v;
    }

    // ---- phase 2c: scan this batch's edges, push (other,gid) to row lists ----
    {
        int probe = ((const int*)edge_mask)[lane];
        bool byte_mask = __any(probe != 0 && probe != 1);
        int ebase = b * 2 * E_;
        const unsigned char* m8  = (const unsigned char*)edge_mask;
        const int*           m32 = (const int*)edge_mask;
        for (int e = tid; e < E_; e += 512) {
            int gid = b * E_ + e;
            bool m = byte_mask ? (m8[gid] != 0) : (m32[gid] != 0);
            if (!m) continue;
            int s = edge_index[ebase + e];
            int t = edge_index[ebase + E_ + e];
            if (s < 0 || s >= NN_ || t < 0 || t >= NN_) continue;
            if (s == 0 && t == 0) continue;
            int s1 = s + 1, t1 = t + 1;
            if (s1 >= i0 && s1 < i0 + SPAN_) {
                int rl = s1 - i0;
                int p = atomicAdd(&sCnt[rl], 1);
                if (p < CAP_) sListM[rl * CAP_ + p] = (t1 << 17) | gid;
            }
            if (t1 >= i0 && t1 < i0 + SPAN_) {
                int rl = t1 - i0;
                int p = atomicAdd(&sCnt[rl], 1);
                if (p < CAP_) sListM[rl * CAP_ + p] = (s1 << 17) | gid;
            }
        }
    }
    __syncthreads();

    // ---- phase 3: convert entries to (meta, dist) ----
    {
        int nl = nlig[b];
        for (int j = tid; j < SPAN_ * CAP_; j += 512) {
            int rl = j >> 7, slp = j & (CAP_ - 1);
            int c = sCnt[rl]; c = c < CAP_ ? c : CAP_;
            if (slp >= c) continue;
            int entry = sListM[j];
            int gid   = entry & 0x1FFFF;
            int other = entry >> 17;
            float4 ef = edge_feat[gid];
            int c0 = (int)ef.x, c1 = (int)ef.y, c2 = (int)ef.z;
            float dist = ef.w;
            int r;
            if (c0 == 0 || c0 == 1) {
                r = min(max(c0 * 4 + c1 * 2 + c2, 0), 19);
            } else if (c0 == 5) {
                int pi = min(max(c1, 0), 14);
                int self_n = i0 + rl - 1, other_n = other - 1;
                int nlg = (self_n < nl ? 1 : 0) + (other_n < nl ? 1 : 0);
                int loc = (nlg == 2) ? 0 : ((nlg == 0) ? 1 : 2);
                r = 20 + loc * 15 + pi;
            } else r = 65;
            int lo = 0;
#pragma unroll
            for (int k = 0; k < 32; ++k) lo += (sT[k] < dist) ? 1 : 0;
            sListM[j] = (lo << 16) | (r << 9) | other;
            sListD[j] = dist;
        }
    }
    __syncthreads();                 // last block barrier

    // ---- phase 4: wave-private row loop (no barriers) ----
    int hh_q = lane & 1;             // plane within wave's pair
    int slot = lane >> 1;            // entry slot 0..31
    int hhg  = (wv << 1) | hh_q;     // hh within half
    int hq   = h0 + hhg;
    float* sW = srow + (wv << 1) * STRIDE_;   // wave-private strip (2 rows)

    int rw = lane >> 5;              // writeout plane 0..1 per 32-lane group
    int sl = lane & 31;
    int hw = h0 + (wv << 1) + rw;
    float vw0 = virtual_w[h0 + (wv << 1)];
    float vw1 = virtual_w[h0 + (wv << 1) + 1];

#pragma unroll 1
    for (int ii = 0; ii < SPAN_; ++ii) {
        int i = i0 + ii;

        // init wave strip (2 rows)
#pragma unroll
        for (int r = 0; r < 2; ++r) {
            float vwr = (r == 0) ? vw0 : vw1;
            float fill = (i == 0) ? vwr : 0.0f;
            float4 f4 = make_float4(fill, fill, fill, fill);
            float4* rp = reinterpret_cast<float4*>(sW + r * STRIDE_);
            for (int c = lane; c < STRIDE_ / 4; c += 64) rp[c] = f4;
        }
        if (i != 0 && lane < 2) {    // virtual column t=0 (disjoint from scatter)
            int hr = h0 + (wv << 1) + lane;
            int off = (4 - ((hr + i) & 3)) & 3;
            sW[lane * STRIDE_ + 4 - off] = (lane == 0) ? vw0 : vw1;
        }

        // gather (all LDS; wave-private)
        int c = sCnt[ii]; c = c < CAP_ ? c : CAP_;
        int offq = (4 - ((hq + i) & 3)) & 3;
        int base = hh_q * STRIDE_ + 4 - offq;
        int bb = ii * CAP_;
        for (int j = slot; j < c; j += 32) {
            int   meta = sListM[bb + j];
            float dist = sListD[bb + j];
            int other = meta & 0x1FF;
            int r     = (meta >> 9) & 0x7F;
            int lo    = meta >> 16;
            float acc = fmaf(dist, sB[lo * TS_ + hhg], sA[lo * TS_ + hhg])
                      + sType[r * TS_ + hhg];
            atomicAdd(&sW[base + other], acc);
        }

        // writeout (wave-private; per-wave LDS ordering)
        {
            const float* rr = sW + rw * STRIDE_;
            float* dst = out + ((size_t)(b * H_ + hw)) * PLANE_ + (size_t)i * N1_;
            int off = (4 - ((hw + i) & 3)) & 3;
            if (sl < off) dst[sl] = rr[4 - off + sl];
            int nvec = (N1_ - off) >> 2;            // 95 or 96
            for (int q = sl; q < nvec; q += 32) {   // 3 iterations
                float4 v = *reinterpret_cast<const float4*>(rr + 4 + 4 * q);
                *reinterpret_cast<float4*>(dst + off + 4 * q) = v;
            }
            int done = off + (nvec << 2);
            int rem = N1_ - done;                   // 0..3
            if (sl < rem) dst[done + sl] = rr[4 + 4 * nvec + sl];
        }
    }
}

// ============================================================================
extern "C" void kernel_launch(void* const* d_in, const int* in_sizes, int n_in,
                              void* d_out, int out_size, void* d_ws, size_t ws_size,
                              hipStream_t stream)
{
    const float4* edge_feat      = (const float4*)d_in[0];
    const int*    edge_index     = (const int*)  d_in[2];
    const void*   edge_mask      =               d_in[3];
    const int*    nlig           = (const int*)  d_in[4];
    const float*  structural_w   = (const float*)d_in[5];
    const float*  plip_protein_w = (const float*)d_in[6];
    const float*  plip_ligand_w  = (const float*)d_in[7];
    const float*  plip_inter_w   = (const float*)d_in[8];
    const float*  loc_w          = (const float*)d_in[9];
    const float*  virtual_w      = (const float*)d_in[10];
    const float*  W1             = (const float*)d_in[11];
    const float*  b1             = (const float*)d_in[12];
    const float*  W2             = (const float*)d_in[13];
    const float*  b2             = (const float*)d_in[14];
    float* out = (float*)d_out;

    fused_kernel<<<GRID_, 512, 0, stream>>>(
        edge_feat, edge_index, edge_mask, nlig,
        structural_w, plip_protein_w, plip_ligand_w, plip_inter_w,
        loc_w, virtual_w, W1, b1, W2, b2, out);
}